// Round 9
// baseline (598.715 us; speedup 1.0000x reference)
//
#include <hip/hip_runtime.h>

// ---- problem constants ----
#define TT   512
#define BI   12
#define HH   50
#define BB   4     // batch per block (R18: halved -> 2 blocks/CU)
#define BTOT 2048
#define LOG2E 1.4426950408889634f

// R18 = R17 (295 us; VALUBusy 42, MfmaUtil 24, ~35% idle, Occupancy 45%)
// at BB=4 with TWO INDEPENDENT BLOCKS PER CU:
//  - the residual idle is the post-barrier read+MFMA window (ds_read
//    ~120cy + MFMA chain ~100cy) where ALL waves of a barrier group have
//    no VALU work (lockstep). Intra-block phase splits lose to barrier
//    cost (R15). Fix: occupancy. 512 blocks x 896 threads (14 waves):
//    1792 threads/CU -> 2 co-resident blocks with UNCORRELATED barriers;
//    block A's act fills block B's read window and vice versa.
//  - cost (accepted): weight-side work duplicates per CU (156 MFMA, 26
//    act bundles with half-valid lanes) -- fits the measured headroom
//    (true MFMA-pipe use ~8%, VALU 42%).
//  - 14-wave block: waves 0-12 compute (R17 merged-layer roles, tile =
//    wv), wave 13 = x-duty on lanes 0-47 (48 = BB*BI slots).
//  - wvalid += (bcol < 4): cols 4-7 of the fragment are unused at BB=4.
// Watch: OccupancyPercent ~45 -> co-residency FAILED (result = noise).
// Carried from R17: one wave = one M-tile = both layers (acc0 L0 2-chain,
// acc1 L1 4-chain, dppmerge slot0=L0/slot1=L1, one act bundle/wave);
// trans fusion (5 exp2 + 2 rcp, clamp 60); scales folded into f16
// weights; fzero C-operand; B0s=[h0|x|bias], B1s=[h1|bias] ping-pong;
// one barrier/step; l0->h0[t], l1->h1[t-1]; 2-ahead xhold prefetch;
// setprio(1) on compute waves.

typedef _Float16 half8 __attribute__((ext_vector_type(8)));
typedef float    f4    __attribute__((ext_vector_type(4)));

__device__ __forceinline__ float sigm_(float v) {
    return __builtin_amdgcn_rcpf(1.f + __builtin_amdgcn_exp2f(v * (-LOG2E)));
}
// lanes with (lane&15)<8 keep a0; lanes with (lane&15)>=8 take a1 from
// lane^8 (DPP row_ror:8 = 0x128, banks 2,3 -> bank_mask 0xC). One VALU op.
__device__ __forceinline__ float dppmerge_(float a0, float a1) {
    int r = __builtin_amdgcn_update_dpp(__builtin_bit_cast(int, a0),
                                        __builtin_bit_cast(int, a1),
                                        0x128, 0xF, 0xC, false);
    return __builtin_bit_cast(float, r);
}

__launch_bounds__(896, 7)
__global__ void lstm2_kernel(const float* __restrict__ x,
                             const float* __restrict__ w_ih0, const float* __restrict__ w_hh0,
                             const float* __restrict__ b_ih0, const float* __restrict__ b_hh0,
                             const float* __restrict__ w_ih1, const float* __restrict__ w_hh1,
                             const float* __restrict__ b_ih1, const float* __restrict__ b_hh1,
                             const float* __restrict__ w_out, const float* __restrict__ b_out,
                             float* __restrict__ out)
{
    const int tid   = threadIdx.x;
    const int wv    = tid >> 6;          // 0..13
    const int lane  = tid & 63;
    const int b0    = blockIdx.x * BB;

    const int m    = lane & 15;
    const int q    = lane >> 4;          // 0..3
    const int slot = m >> 3;             // 0: L0 role, 1: L1 role
    const int bcol = m & 7;
    const int T    = wv;                 // M-tile (compute waves only)
    const bool comp = (wv < 13);
    const int u_m  = T * 4 + q;          // unit owned by this lane
    const bool wvalid = comp && (u_m < HH) && (bcol < BB);

    if (comp) __builtin_amdgcn_s_setprio(1);

    // K-space: B0s rows = [h0: 0-49 | x: 50-61 | bias(=1): 62 | pad: 63]
    //          B1s rows = [h1: 0-49 | unused: 50-61 | bias(=1): 62 | pad: 63]
    __shared__ __align__(16) _Float16 B0s[2][64 * 16];
    __shared__ __align__(16) _Float16 B1s[2][64 * 16];

    // ---- step-invariant A fragments (pre-scaled), tile T, both layers ----
    const int uA = T * 4 + (m >> 2);     // A-fragment row unit
    const int gA = m & 3;                // gate
    half8 af0[2], af1[4];
    #pragma unroll
    for (int kb = 0; kb < 2; kb++) {
        #pragma unroll
        for (int j = 0; j < 8; j++) {
            float v = 0.f;
            if (comp && uA < HH) {
                const int r  = gA * HH + uA;
                const int kg = kb * 32 + q * 8 + j;
                if      (kg < 50)  v = w_hh0[r * HH + kg];
                else if (kg < 62)  v = w_ih0[r * BI + (kg - 50)];
                else if (kg == 62) v = b_ih0[r] + b_hh0[r];
                v *= (gA == 2) ? (2.f * LOG2E) : (-LOG2E);
            }
            af0[kb][j] = (_Float16)v;
        }
    }
    #pragma unroll
    for (int kb = 0; kb < 4; kb++) {
        #pragma unroll
        for (int j = 0; j < 8; j++) {
            float v = 0.f;
            if (comp && uA < HH) {
                const int r  = gA * HH + uA;
                const int kg = kb * 32 + q * 8 + j;
                if      (kg < 50)               v = w_ih1[r * HH + kg];
                else if (kg >= 64 && kg < 114)  v = w_hh1[r * HH + (kg - 64)];
                else if (kg == 126)             v = b_ih1[r] + b_hh1[r];
                v *= (gA == 2) ? (2.f * LOG2E) : (-LOG2E);
            }
            af1[kb][j] = (_Float16)v;
        }
    }

    // ---- init LDS ----
    for (int i = tid; i < 2 * 64 * 16; i += 896) {
        (&B0s[0][0])[i] = (_Float16)0.f;
        (&B1s[0][0])[i] = (_Float16)0.f;
    }
    __syncthreads();
    if (tid < 16) {                       // bias (ones) row 62, both parities
        B0s[0][7 * 128 + tid * 8 + 6] = (_Float16)1.f;
        B0s[1][7 * 128 + tid * 8 + 6] = (_Float16)1.f;
        B1s[0][7 * 128 + tid * 8 + 6] = (_Float16)1.f;
        B1s[1][7 * 128 + tid * 8 + 6] = (_Float16)1.f;
    }

    // ---- x-duty: wave 13, lanes 0-47 -> 48 slots = BB*BI ----
    const bool xact = (wv == 13) && (lane < BB * BI);
    const int xidx  = lane;                                // 0..47 on xact
    const int xb    = xidx / 12, xi = xidx - xb * 12;
    const int xrow  = 50 + xi;
    const int xoff  = (xrow >> 3) * 128 + xb * 8 + (xrow & 7);
    const size_t xbase = ((size_t)(b0 + xb) * TT) * BI + xi;
    if (xact)                              // x[0] -> parity 0
        B0s[0][xoff] = (_Float16)x[xbase];
    __syncthreads();

    // ---- per-parity pointers (loop-invariant) ----
    const _Float16* rd0[2] = { &B0s[0][0] + lane * 8, &B0s[1][0] + lane * 8 };
    const _Float16* rd1[2] = { &B1s[0][0] + lane * 8, &B1s[1][0] + lane * 8 };
    const int offA = (u_m >> 3) * 128 + bcol * 8 + (u_m & 7);   // h row = u_m
    _Float16* wAp[2] = { (slot ? &B1s[0][0] : &B0s[0][0]) + offA,
                         (slot ? &B1s[1][0] : &B0s[1][0]) + offA };
    _Float16* xdp[2] = { &B0s[0][0] + xoff, &B0s[1][0] + xoff };

    const f4 fzero = {0.f, 0.f, 0.f, 0.f};
    float cm = 0.f;                        // cell state for (slot-layer, u_m, bcol)

    // x stream, 2-step-ahead: xhold carries x[t+1] across a full step.
    const float* xq = x + xbase + BI;     // points at x[1]
    float xhold = 0.f;
    if (xact) xhold = *xq;                // preload x[1]
    xq += BI;                             // points at x[2]

// One timestep at compile-time parity P (flags/parity as R16/R17).
// Per-lane activity: slot0 lanes live iff DOL0, slot1 iff DOL1 (folds to
// true in the main loop). MFMAs run unconditionally on compute waves
// (stale operands in peel steps are discarded by the predicate).
#define STEP(P, DOL0, DOL1, DOST, DOLD)                                       \
  {                                                                           \
    float xnew = 0.f;                                                         \
    if ((DOLD) && xact) xnew = *xq;                                           \
    if ((DOST) && xact) *xdp[1 - (P)] = (_Float16)xhold;                      \
    if (comp) {                                                               \
      const half8 bf0 = *(const half8*)(rd0[P]);                              \
      const half8 bf1 = *(const half8*)(rd0[P] + 512);                        \
      const half8 bf2 = *(const half8*)(rd1[P]);                              \
      const half8 bf3 = *(const half8*)(rd1[P] + 512);                        \
      f4 acc0, acc1;                                                          \
      acc0 = __builtin_amdgcn_mfma_f32_16x16x32_f16(af0[0], bf0, fzero, 0, 0, 0); \
      acc0 = __builtin_amdgcn_mfma_f32_16x16x32_f16(af0[1], bf1, acc0, 0, 0, 0);  \
      acc1 = __builtin_amdgcn_mfma_f32_16x16x32_f16(af1[0], bf0, fzero, 0, 0, 0); \
      acc1 = __builtin_amdgcn_mfma_f32_16x16x32_f16(af1[1], bf1, acc1, 0, 0, 0);  \
      acc1 = __builtin_amdgcn_mfma_f32_16x16x32_f16(af1[2], bf2, acc1, 0, 0, 0);  \
      acc1 = __builtin_amdgcn_mfma_f32_16x16x32_f16(af1[3], bf3, acc1, 0, 0, 0);  \
      f4 am;                                                                  \
      _Pragma("unroll")                                                       \
      for (int i = 0; i < 4; i++) am[i] = dppmerge_(acc0[i], acc1[i]);        \
      const float eI = __builtin_amdgcn_exp2f(am[0]);                         \
      const float eF = __builtin_amdgcn_exp2f(am[1]);                         \
      const float eG = __builtin_amdgcn_exp2f(am[2]);                         \
      const float eO = __builtin_amdgcn_exp2f(am[3]);                         \
      const float dI = 1.f + eI, dF = 1.f + eF;                               \
      const float dG = 1.f + eG, dO = 1.f + eO;                               \
      const float pIG = dI * dG;                                              \
      const float num = __builtin_fmaf(cm, pIG, (eG - 1.f) * dF);             \
      const float cmn = num * __builtin_amdgcn_rcpf(dF * pIG);                \
      const float uu  = fminf(cmn * (2.f * LOG2E), 60.f);                     \
      const float eC  = __builtin_amdgcn_exp2f(uu);                           \
      const float h   = (eC - 1.f) * __builtin_amdgcn_rcpf(dO * (1.f + eC));  \
      const bool actp = slot ? (bool)(DOL1) : (bool)(DOL0);                   \
      if (actp) cm = cmn;                                                     \
      if (actp && wvalid) *wAp[1 - (P)] = (_Float16)h;                        \
    }                                                                         \
    if (DOLD) { xhold = xnew; xq += BI; }                                     \
    __syncthreads();                                                          \
  }

    STEP(0, 1, 0, 1, 1)                   // t = 0   (l0 only; store x[1], load x[2])
    STEP(1, 1, 1, 1, 1)                   // t = 1
    #pragma unroll 1
    for (int it = 0; it < 254; ++it) {    // t = 2 .. 509
        STEP(0, 1, 1, 1, 1)
        STEP(1, 1, 1, 1, 1)
    }
    STEP(0, 1, 1, 1, 0)                   // t = 510 (store x[511], no more loads)
    STEP(1, 1, 1, 0, 0)                   // t = 511
    STEP(0, 0, 1, 0, 0)                   // t = 512 (l1 drain: h1[511] -> B1s[1])
#undef STEP

    // ---- epilogue: sigmoid(h1[TT-1] . w_out + b_out); h1[511] in B1s[1] ----
    if (tid < BB) {
        float s = b_out[0];
        #pragma unroll
        for (int u = 0; u < HH; u++) {
            s += w_out[u] * (float)B1s[1][(u >> 3) * 128 + tid * 8 + (u & 7)];
        }
        out[b0 + tid] = sigm_(s);
    }
}

extern "C" void kernel_launch(void* const* d_in, const int* in_sizes, int n_in,
                              void* d_out, int out_size, void* d_ws, size_t ws_size,
                              hipStream_t stream) {
    const float* x     = (const float*)d_in[0];
    const float* w_ih0 = (const float*)d_in[1];
    const float* w_hh0 = (const float*)d_in[2];
    const float* b_ih0 = (const float*)d_in[3];
    const float* b_hh0 = (const float*)d_in[4];
    const float* w_ih1 = (const float*)d_in[5];
    const float* w_hh1 = (const float*)d_in[6];
    const float* b_ih1 = (const float*)d_in[7];
    const float* b_hh1 = (const float*)d_in[8];
    const float* w_out = (const float*)d_in[9];
    const float* b_out = (const float*)d_in[10];
    float* out = (float*)d_out;

    dim3 grid(BTOT / BB);   // 512 blocks -> 2 per CU (independent barriers)
    dim3 block(896);        // 14 waves: 13 merged-layer compute + 1 x-wave
    lstm2_kernel<<<grid, block, 0, stream>>>(x, w_ih0, w_hh0, b_ih0, b_hh0,
                                             w_ih1, w_hh1, b_ih1, b_hh1,
                                             w_out, b_out, out);
}

// Round 10
// 503.868 us; speedup vs baseline: 1.1882x; 1.1882x over previous
//
#include <hip/hip_runtime.h>

// ---- problem constants ----
#define TT   512
#define BI   12
#define HH   50
#define BB   4     // batch per block -> 2 co-resident blocks per CU
#define BTOT 2048
#define LOG2E 1.4426950408889634f

// R19 = R18's occupancy play with SCHEDULABLE packaging. R18 post-mortem:
// 896-thr (14-wave) blocks land 4,4,3,3 on the SIMDs; two need 8,8,6,6 =
// exactly at the 8-wave/SIMD cap -> scheduler refused, grid ran as two
// sequential passes (565us = 2x283). Fix: 512-thr (8-wave) blocks pack
// 2,2,2,2 each -> two blocks = 4,4,4,4 per CU, well inside caps.
//  - waves 0-5: TWO M-tiles x both layers each (TA=2w, TB=2w+1): 12 MFMA,
//    2 act bundles, but only 4 shared ds_read_b128 (block reads 52->28).
//  - wave 6: tile 12 (6 MFMA, 1 bundle). wave 7: x-duty (48 = BB*BI
//    slots, lanes 0-47).
//  - 2 blocks/CU with INDEPENDENT barriers: block A's act fills block B's
//    post-barrier read+MFMA window (the ~35% lockstep idle R15's
//    intra-block stagger could not recover). Cost: x2 weight-side
//    duplication per CU (156 MFMA, 26 bundles) -- fits measured headroom
//    (MFMA pipe ~8%, VALU 42%).
//  - __launch_bounds__(512,4) caps VGPR at 128 (est ~115) to guarantee
//    4 waves/SIMD capacity.
// Carried from R17: merged-layer lanes (slot0=L0, slot1=L1 via dppmerge),
// trans fusion (5 exp2 + 2 rcp, clamp 60), scales folded into f16
// weights, fzero C-operand, B0s=[h0|x|bias] / B1s=[h1|bias] ping-pong,
// one barrier/step, l0->h0[t] l1->h1[t-1] pipeline, 2-ahead xhold
// prefetch, setprio(1) on compute waves.
// Failure signatures: dur ~560 (serialized) or ~300 (phase-locked) ->
// revert to R17.

typedef _Float16 half8 __attribute__((ext_vector_type(8)));
typedef float    f4    __attribute__((ext_vector_type(4)));

__device__ __forceinline__ float sigm_(float v) {
    return __builtin_amdgcn_rcpf(1.f + __builtin_amdgcn_exp2f(v * (-LOG2E)));
}
// lanes with (lane&15)<8 keep a0; lanes with (lane&15)>=8 take a1 from
// lane^8 (DPP row_ror:8 = 0x128, banks 2,3 -> bank_mask 0xC). One VALU op.
__device__ __forceinline__ float dppmerge_(float a0, float a1) {
    int r = __builtin_amdgcn_update_dpp(__builtin_bit_cast(int, a0),
                                        __builtin_bit_cast(int, a1),
                                        0x128, 0xF, 0xC, false);
    return __builtin_bit_cast(float, r);
}

__launch_bounds__(512, 4)
__global__ void lstm2_kernel(const float* __restrict__ x,
                             const float* __restrict__ w_ih0, const float* __restrict__ w_hh0,
                             const float* __restrict__ b_ih0, const float* __restrict__ b_hh0,
                             const float* __restrict__ w_ih1, const float* __restrict__ w_hh1,
                             const float* __restrict__ b_ih1, const float* __restrict__ b_hh1,
                             const float* __restrict__ w_out, const float* __restrict__ b_out,
                             float* __restrict__ out)
{
    const int tid   = threadIdx.x;
    const int wv    = tid >> 6;          // 0..7
    const int lane  = tid & 63;
    const int b0    = blockIdx.x * BB;

    const int m    = lane & 15;
    const int q    = lane >> 4;          // 0..3 (unit within tile)
    const int slot = m >> 3;             // 0: L0 role, 1: L1 role
    const int bcol = m & 7;
    const bool comp = (wv < 7);
    const bool hasB = (wv < 6);
    const int TA   = (wv < 6) ? 2 * wv : 12;   // first tile
    const int TB   = 2 * wv + 1;               // second tile (hasB only)
    const int uAm  = TA * 4 + q;
    const int uBm  = TB * 4 + q;
    const bool wvalidA = comp && (uAm < HH) && (bcol < BB);
    const bool wvalidB = hasB && (bcol < BB);  // uBm <= 47 < HH always

    if (comp) __builtin_amdgcn_s_setprio(1);

    // K-space: B0s rows = [h0: 0-49 | x: 50-61 | bias(=1): 62 | pad: 63]
    //          B1s rows = [h1: 0-49 | unused: 50-61 | bias(=1): 62 | pad: 63]
    __shared__ __align__(16) _Float16 B0s[2][64 * 16];
    __shared__ __align__(16) _Float16 B1s[2][64 * 16];

    // ---- step-invariant A fragments (pre-scaled), tiles TA/TB, both layers ----
    const int gA = m & 3;                // gate
    half8 afA0[2], afA1[4], afB0[2], afB1[4];
    #pragma unroll
    for (int p = 0; p < 2; p++) {        // p=0: tile TA, p=1: tile TB
        const int Tp = p ? TB : TA;
        const int uF = Tp * 4 + (m >> 2);
        const bool ok = p ? hasB : comp;
        #pragma unroll
        for (int kb = 0; kb < 2; kb++) {
            #pragma unroll
            for (int j = 0; j < 8; j++) {
                float v = 0.f;
                if (ok && uF < HH) {
                    const int r  = gA * HH + uF;
                    const int kg = kb * 32 + q * 8 + j;
                    if      (kg < 50)  v = w_hh0[r * HH + kg];
                    else if (kg < 62)  v = w_ih0[r * BI + (kg - 50)];
                    else if (kg == 62) v = b_ih0[r] + b_hh0[r];
                    v *= (gA == 2) ? (2.f * LOG2E) : (-LOG2E);
                }
                (p ? afB0 : afA0)[kb][j] = (_Float16)v;
            }
        }
        #pragma unroll
        for (int kb = 0; kb < 4; kb++) {
            #pragma unroll
            for (int j = 0; j < 8; j++) {
                float v = 0.f;
                if (ok && uF < HH) {
                    const int r  = gA * HH + uF;
                    const int kg = kb * 32 + q * 8 + j;
                    if      (kg < 50)               v = w_ih1[r * HH + kg];
                    else if (kg >= 64 && kg < 114)  v = w_hh1[r * HH + (kg - 64)];
                    else if (kg == 126)             v = b_ih1[r] + b_hh1[r];
                    v *= (gA == 2) ? (2.f * LOG2E) : (-LOG2E);
                }
                (p ? afB1 : afA1)[kb][j] = (_Float16)v;
            }
        }
    }

    // ---- init LDS ----
    for (int i = tid; i < 2 * 64 * 16; i += 512) {
        (&B0s[0][0])[i] = (_Float16)0.f;
        (&B1s[0][0])[i] = (_Float16)0.f;
    }
    __syncthreads();
    if (tid < 16) {                       // bias (ones) row 62, both parities
        B0s[0][7 * 128 + tid * 8 + 6] = (_Float16)1.f;
        B0s[1][7 * 128 + tid * 8 + 6] = (_Float16)1.f;
        B1s[0][7 * 128 + tid * 8 + 6] = (_Float16)1.f;
        B1s[1][7 * 128 + tid * 8 + 6] = (_Float16)1.f;
    }

    // ---- x-duty: wave 7, lanes 0-47 -> 48 slots = BB*BI ----
    const bool xact = (wv == 7) && (lane < BB * BI);
    const int xb    = lane / 12, xi = lane - xb * 12;
    const int xrow  = 50 + xi;
    const int xoff  = (xrow >> 3) * 128 + xb * 8 + (xrow & 7);
    const size_t xbase = ((size_t)(b0 + xb) * TT) * BI + xi;
    if (xact)                              // x[0] -> parity 0
        B0s[0][xoff] = (_Float16)x[xbase];
    __syncthreads();

    // ---- per-parity pointers (loop-invariant) ----
    const _Float16* rd0[2] = { &B0s[0][0] + lane * 8, &B0s[1][0] + lane * 8 };
    const _Float16* rd1[2] = { &B1s[0][0] + lane * 8, &B1s[1][0] + lane * 8 };
    const int offAA = (uAm >> 3) * 128 + bcol * 8 + (uAm & 7);
    const int offAB = (uBm >> 3) * 128 + bcol * 8 + (uBm & 7);
    _Float16* wApA[2] = { (slot ? &B1s[0][0] : &B0s[0][0]) + offAA,
                          (slot ? &B1s[1][0] : &B0s[1][0]) + offAA };
    _Float16* wApB[2] = { (slot ? &B1s[0][0] : &B0s[0][0]) + offAB,
                          (slot ? &B1s[1][0] : &B0s[1][0]) + offAB };
    _Float16* xdp[2] = { &B0s[0][0] + xoff, &B0s[1][0] + xoff };

    const f4 fzero = {0.f, 0.f, 0.f, 0.f};
    float cmA = 0.f, cmB = 0.f;           // cell states (slot-layer, u, bcol)

    // x stream, 2-step-ahead: xhold carries x[t+1] across a full step.
    const float* xq = x + xbase + BI;     // points at x[1]
    float xhold = 0.f;
    if (xact) xhold = *xq;                // preload x[1]
    xq += BI;                             // points at x[2]

// Fused act + cell update + write (exact algebra, R12-verified).
#define DOACT(AM, CM, WPTR, WOK, ACTP)                                        \
  {                                                                           \
    const float eI = __builtin_amdgcn_exp2f((AM)[0]);                         \
    const float eF = __builtin_amdgcn_exp2f((AM)[1]);                         \
    const float eG = __builtin_amdgcn_exp2f((AM)[2]);                         \
    const float eO = __builtin_amdgcn_exp2f((AM)[3]);                         \
    const float dI = 1.f + eI, dF = 1.f + eF;                                 \
    const float dG = 1.f + eG, dO = 1.f + eO;                                 \
    const float pIG = dI * dG;                                                \
    const float num = __builtin_fmaf(CM, pIG, (eG - 1.f) * dF);               \
    const float cmn = num * __builtin_amdgcn_rcpf(dF * pIG);                  \
    const float uu  = fminf(cmn * (2.f * LOG2E), 60.f);                       \
    const float eC  = __builtin_amdgcn_exp2f(uu);                             \
    const float h_  = (eC - 1.f) * __builtin_amdgcn_rcpf(dO * (1.f + eC));    \
    if (ACTP) CM = cmn;                                                       \
    if ((ACTP) && (WOK)) *(WPTR) = (_Float16)h_;                              \
  }

// One timestep at compile-time parity P (flags/parity as R16/R17).
#define STEP(P, DOL0, DOL1, DOST, DOLD)                                       \
  {                                                                           \
    float xnew = 0.f;                                                         \
    if ((DOLD) && xact) xnew = *xq;                                           \
    if ((DOST) && xact) *xdp[1 - (P)] = (_Float16)xhold;                      \
    if (comp) {                                                               \
      const half8 bf0 = *(const half8*)(rd0[P]);                              \
      const half8 bf1 = *(const half8*)(rd0[P] + 512);                        \
      const half8 bf2 = *(const half8*)(rd1[P]);                              \
      const half8 bf3 = *(const half8*)(rd1[P] + 512);                        \
      const bool actp = slot ? (bool)(DOL1) : (bool)(DOL0);                   \
      f4 a0, a1;                                                              \
      a0 = __builtin_amdgcn_mfma_f32_16x16x32_f16(afA0[0], bf0, fzero, 0, 0, 0); \
      a0 = __builtin_amdgcn_mfma_f32_16x16x32_f16(afA0[1], bf1, a0, 0, 0, 0);    \
      a1 = __builtin_amdgcn_mfma_f32_16x16x32_f16(afA1[0], bf0, fzero, 0, 0, 0); \
      a1 = __builtin_amdgcn_mfma_f32_16x16x32_f16(afA1[1], bf1, a1, 0, 0, 0);    \
      a1 = __builtin_amdgcn_mfma_f32_16x16x32_f16(afA1[2], bf2, a1, 0, 0, 0);    \
      a1 = __builtin_amdgcn_mfma_f32_16x16x32_f16(afA1[3], bf3, a1, 0, 0, 0);    \
      f4 amA;                                                                 \
      _Pragma("unroll")                                                       \
      for (int i = 0; i < 4; i++) amA[i] = dppmerge_(a0[i], a1[i]);           \
      if (hasB) {                                                             \
        f4 b0v, b1v;                                                          \
        b0v = __builtin_amdgcn_mfma_f32_16x16x32_f16(afB0[0], bf0, fzero, 0, 0, 0); \
        b0v = __builtin_amdgcn_mfma_f32_16x16x32_f16(afB0[1], bf1, b0v, 0, 0, 0);   \
        b1v = __builtin_amdgcn_mfma_f32_16x16x32_f16(afB1[0], bf0, fzero, 0, 0, 0); \
        b1v = __builtin_amdgcn_mfma_f32_16x16x32_f16(afB1[1], bf1, b1v, 0, 0, 0);   \
        b1v = __builtin_amdgcn_mfma_f32_16x16x32_f16(afB1[2], bf2, b1v, 0, 0, 0);   \
        b1v = __builtin_amdgcn_mfma_f32_16x16x32_f16(afB1[3], bf3, b1v, 0, 0, 0);   \
        f4 amB;                                                               \
        _Pragma("unroll")                                                     \
        for (int i = 0; i < 4; i++) amB[i] = dppmerge_(b0v[i], b1v[i]);       \
        DOACT(amA, cmA, wApA[1 - (P)], wvalidA, actp)                         \
        DOACT(amB, cmB, wApB[1 - (P)], wvalidB, actp)                         \
      } else {                                                                \
        DOACT(amA, cmA, wApA[1 - (P)], wvalidA, actp)                         \
      }                                                                       \
    }                                                                         \
    if (DOLD) { xhold = xnew; xq += BI; }                                     \
    __syncthreads();                                                          \
  }

    STEP(0, 1, 0, 1, 1)                   // t = 0   (l0 only; store x[1], load x[2])
    STEP(1, 1, 1, 1, 1)                   // t = 1
    #pragma unroll 1
    for (int it = 0; it < 254; ++it) {    // t = 2 .. 509
        STEP(0, 1, 1, 1, 1)
        STEP(1, 1, 1, 1, 1)
    }
    STEP(0, 1, 1, 1, 0)                   // t = 510 (store x[511], no more loads)
    STEP(1, 1, 1, 0, 0)                   // t = 511
    STEP(0, 0, 1, 0, 0)                   // t = 512 (l1 drain: h1[511] -> B1s[1])
#undef STEP
#undef DOACT

    // ---- epilogue: sigmoid(h1[TT-1] . w_out + b_out); h1[511] in B1s[1] ----
    if (tid < BB) {
        float s = b_out[0];
        #pragma unroll
        for (int u = 0; u < HH; u++) {
            s += w_out[u] * (float)B1s[1][(u >> 3) * 128 + tid * 8 + (u & 7)];
        }
        out[b0 + tid] = sigm_(s);
    }
}

extern "C" void kernel_launch(void* const* d_in, const int* in_sizes, int n_in,
                              void* d_out, int out_size, void* d_ws, size_t ws_size,
                              hipStream_t stream) {
    const float* x     = (const float*)d_in[0];
    const float* w_ih0 = (const float*)d_in[1];
    const float* w_hh0 = (const float*)d_in[2];
    const float* b_ih0 = (const float*)d_in[3];
    const float* b_hh0 = (const float*)d_in[4];
    const float* w_ih1 = (const float*)d_in[5];
    const float* w_hh1 = (const float*)d_in[6];
    const float* b_ih1 = (const float*)d_in[7];
    const float* b_hh1 = (const float*)d_in[8];
    const float* w_out = (const float*)d_in[9];
    const float* b_out = (const float*)d_in[10];
    float* out = (float*)d_out;

    dim3 grid(BTOT / BB);   // 512 blocks -> 2 per CU (8-wave packing: 4,4,4,4)
    dim3 block(512);        // 8 waves: 6x 2-tile + 1x 1-tile + 1 x-wave
    lstm2_kernel<<<grid, block, 0, stream>>>(x, w_ih0, w_hh0, b_ih0, b_hh0,
                                             w_ih1, w_hh1, b_ih1, b_hh1,
                                             w_out, b_out, out);
}

// Round 11
// 365.851 us; speedup vs baseline: 1.6365x; 1.3772x over previous
//
#include <hip/hip_runtime.h>

// ---- problem constants ----
#define TT   512
#define BI   12
#define HH   50
#define BB   8     // batch per block -> ONE 8-wave block per CU
#define BTOT 2048
#define LOG2E 1.4426950408889634f

// R20 = R19's dense 8-wave structure at BB=8 / grid 256 (one block/CU).
// R19 post-mortem: 2 co-resident blocks doubled weight-side work but time
// rose only 1.57x -> the 8-wave packaging runs at ~975 cy per R17-work-unit
// vs R17's 1270 cy (denser waves: 2 tiles/wave share 4 ds_read_b128, 4
// independent MFMA chains + 2 independent act bundles of intra-wave ILP).
// R20 keeps R17's total per-CU work (78 MFMA, 13 bundles/step) in that
// packaging: block LDS reads 52->28, 8-wave barrier (less arrival spread),
// per-wave stream long enough to self-overlap instead of relying on
// cross-wave TLP that the lockstep idle destroyed.
//  - waves 0-5: tiles (2w, 2w+1) x both layers; wave 6: tile 12, its dead
//    lanes (q>=2 -> u=50,51 >= HH) take x-slots 64-95; wave 7: x-slots
//    0-63. 96 = BB*BI exactly.
//  - failure signature: dispatch >= 295 (no better than R17) -> revert to
//    R17 and declare.
// Carried from R17/R19: merged-layer lanes (slot0=L0, slot1=L1 via
// dppmerge), trans fusion (5 exp2 + 2 rcp, clamp 60), scales folded into
// f16 weights, fzero C-operand, B0s=[h0 0-49|x 50-61|bias 62] /
// B1s=[h1 0-49|bias 62] ping-pong, one barrier/step, l0->h0[t]
// l1->h1[t-1] pipeline, 2-ahead xhold prefetch, setprio(1) on compute.

typedef _Float16 half8 __attribute__((ext_vector_type(8)));
typedef float    f4    __attribute__((ext_vector_type(4)));

__device__ __forceinline__ float sigm_(float v) {
    return __builtin_amdgcn_rcpf(1.f + __builtin_amdgcn_exp2f(v * (-LOG2E)));
}
// lanes with (lane&15)<8 keep a0; lanes with (lane&15)>=8 take a1 from
// lane^8 (DPP row_ror:8 = 0x128, banks 2,3 -> bank_mask 0xC). One VALU op.
__device__ __forceinline__ float dppmerge_(float a0, float a1) {
    int r = __builtin_amdgcn_update_dpp(__builtin_bit_cast(int, a0),
                                        __builtin_bit_cast(int, a1),
                                        0x128, 0xF, 0xC, false);
    return __builtin_bit_cast(float, r);
}

__launch_bounds__(512, 2)
__global__ void lstm2_kernel(const float* __restrict__ x,
                             const float* __restrict__ w_ih0, const float* __restrict__ w_hh0,
                             const float* __restrict__ b_ih0, const float* __restrict__ b_hh0,
                             const float* __restrict__ w_ih1, const float* __restrict__ w_hh1,
                             const float* __restrict__ b_ih1, const float* __restrict__ b_hh1,
                             const float* __restrict__ w_out, const float* __restrict__ b_out,
                             float* __restrict__ out)
{
    const int tid   = threadIdx.x;
    const int wv    = tid >> 6;          // 0..7
    const int lane  = tid & 63;
    const int b0    = blockIdx.x * BB;

    const int m    = lane & 15;
    const int q    = lane >> 4;          // 0..3 (unit within tile)
    const int slot = m >> 3;             // 0: L0 role, 1: L1 role
    const int bcol = m & 7;
    const bool comp = (wv < 7);
    const bool hasB = (wv < 6);
    const int TA   = (wv < 6) ? 2 * wv : 12;   // first tile
    const int TB   = 2 * wv + 1;               // second tile (hasB only)
    const int uAm  = TA * 4 + q;
    const int uBm  = TB * 4 + q;
    const bool wvalidA = comp && (uAm < HH);
    const bool wvalidB = hasB;                 // uBm <= 47 < HH always

    if (comp) __builtin_amdgcn_s_setprio(1);

    // K-space: B0s rows = [h0: 0-49 | x: 50-61 | bias(=1): 62 | pad: 63]
    //          B1s rows = [h1: 0-49 | unused: 50-61 | bias(=1): 62 | pad: 63]
    __shared__ __align__(16) _Float16 B0s[2][64 * 16];
    __shared__ __align__(16) _Float16 B1s[2][64 * 16];

    // ---- step-invariant A fragments (pre-scaled), tiles TA/TB, both layers ----
    const int gA = m & 3;                // gate
    half8 afA0[2], afA1[4], afB0[2], afB1[4];
    #pragma unroll
    for (int p = 0; p < 2; p++) {        // p=0: tile TA, p=1: tile TB
        const int Tp = p ? TB : TA;
        const int uF = Tp * 4 + (m >> 2);
        const bool ok = p ? hasB : comp;
        #pragma unroll
        for (int kb = 0; kb < 2; kb++) {
            #pragma unroll
            for (int j = 0; j < 8; j++) {
                float v = 0.f;
                if (ok && uF < HH) {
                    const int r  = gA * HH + uF;
                    const int kg = kb * 32 + q * 8 + j;
                    if      (kg < 50)  v = w_hh0[r * HH + kg];
                    else if (kg < 62)  v = w_ih0[r * BI + (kg - 50)];
                    else if (kg == 62) v = b_ih0[r] + b_hh0[r];
                    v *= (gA == 2) ? (2.f * LOG2E) : (-LOG2E);
                }
                (p ? afB0 : afA0)[kb][j] = (_Float16)v;
            }
        }
        #pragma unroll
        for (int kb = 0; kb < 4; kb++) {
            #pragma unroll
            for (int j = 0; j < 8; j++) {
                float v = 0.f;
                if (ok && uF < HH) {
                    const int r  = gA * HH + uF;
                    const int kg = kb * 32 + q * 8 + j;
                    if      (kg < 50)               v = w_ih1[r * HH + kg];
                    else if (kg >= 64 && kg < 114)  v = w_hh1[r * HH + (kg - 64)];
                    else if (kg == 126)             v = b_ih1[r] + b_hh1[r];
                    v *= (gA == 2) ? (2.f * LOG2E) : (-LOG2E);
                }
                (p ? afB1 : afA1)[kb][j] = (_Float16)v;
            }
        }
    }

    // ---- init LDS ----
    for (int i = tid; i < 2 * 64 * 16; i += 512) {
        (&B0s[0][0])[i] = (_Float16)0.f;
        (&B1s[0][0])[i] = (_Float16)0.f;
    }
    __syncthreads();
    if (tid < 16) {                       // bias (ones) row 62, both parities
        B0s[0][7 * 128 + tid * 8 + 6] = (_Float16)1.f;
        B0s[1][7 * 128 + tid * 8 + 6] = (_Float16)1.f;
        B1s[0][7 * 128 + tid * 8 + 6] = (_Float16)1.f;
        B1s[1][7 * 128 + tid * 8 + 6] = (_Float16)1.f;
    }

    // ---- x-duty: wave 7 (slots 0-63) + wave 6 dead lanes q>=2 (slots 64-95) ----
    const bool xact = (wv == 7) || (wv == 6 && lane >= 32);
    const int xidx  = (wv == 7) ? lane : (lane + 32);      // 0..95 on xact
    const int xb    = xidx / 12, xi = xidx - xb * 12;
    const int xrow  = 50 + xi;
    const int xoff  = (xrow >> 3) * 128 + xb * 8 + (xrow & 7);
    const size_t xbase = ((size_t)(b0 + xb) * TT) * BI + xi;
    if (xact)                              // x[0] -> parity 0
        B0s[0][xoff] = (_Float16)x[xbase];
    __syncthreads();

    // ---- per-parity pointers (loop-invariant) ----
    const _Float16* rd0[2] = { &B0s[0][0] + lane * 8, &B0s[1][0] + lane * 8 };
    const _Float16* rd1[2] = { &B1s[0][0] + lane * 8, &B1s[1][0] + lane * 8 };
    const int offAA = (uAm >> 3) * 128 + bcol * 8 + (uAm & 7);
    const int offAB = (uBm >> 3) * 128 + bcol * 8 + (uBm & 7);
    _Float16* wApA[2] = { (slot ? &B1s[0][0] : &B0s[0][0]) + offAA,
                          (slot ? &B1s[1][0] : &B0s[1][0]) + offAA };
    _Float16* wApB[2] = { (slot ? &B1s[0][0] : &B0s[0][0]) + offAB,
                          (slot ? &B1s[1][0] : &B0s[1][0]) + offAB };
    _Float16* xdp[2] = { &B0s[0][0] + xoff, &B0s[1][0] + xoff };

    const f4 fzero = {0.f, 0.f, 0.f, 0.f};
    float cmA = 0.f, cmB = 0.f;           // cell states (slot-layer, u, bcol)

    // x stream, 2-step-ahead: xhold carries x[t+1] across a full step.
    const float* xq = x + xbase + BI;     // points at x[1]
    float xhold = 0.f;
    if (xact) xhold = *xq;                // preload x[1]
    xq += BI;                             // points at x[2]

// Fused act + cell update + write (exact algebra, R12-verified).
#define DOACT(AM, CM, WPTR, WOK, ACTP)                                        \
  {                                                                           \
    const float eI = __builtin_amdgcn_exp2f((AM)[0]);                         \
    const float eF = __builtin_amdgcn_exp2f((AM)[1]);                         \
    const float eG = __builtin_amdgcn_exp2f((AM)[2]);                         \
    const float eO = __builtin_amdgcn_exp2f((AM)[3]);                         \
    const float dI = 1.f + eI, dF = 1.f + eF;                                 \
    const float dG = 1.f + eG, dO = 1.f + eO;                                 \
    const float pIG = dI * dG;                                                \
    const float num = __builtin_fmaf(CM, pIG, (eG - 1.f) * dF);               \
    const float cmn = num * __builtin_amdgcn_rcpf(dF * pIG);                  \
    const float uu  = fminf(cmn * (2.f * LOG2E), 60.f);                       \
    const float eC  = __builtin_amdgcn_exp2f(uu);                             \
    const float h_  = (eC - 1.f) * __builtin_amdgcn_rcpf(dO * (1.f + eC));    \
    if (ACTP) CM = cmn;                                                       \
    if ((ACTP) && (WOK)) *(WPTR) = (_Float16)h_;                              \
  }

// One timestep at compile-time parity P (flags/parity as R16/R17).
#define STEP(P, DOL0, DOL1, DOST, DOLD)                                       \
  {                                                                           \
    float xnew = 0.f;                                                         \
    if ((DOLD) && xact) xnew = *xq;                                           \
    if ((DOST) && xact) *xdp[1 - (P)] = (_Float16)xhold;                      \
    if (comp) {                                                               \
      const half8 bf0 = *(const half8*)(rd0[P]);                              \
      const half8 bf1 = *(const half8*)(rd0[P] + 512);                        \
      const half8 bf2 = *(const half8*)(rd1[P]);                              \
      const half8 bf3 = *(const half8*)(rd1[P] + 512);                        \
      const bool actp = slot ? (bool)(DOL1) : (bool)(DOL0);                   \
      f4 a0, a1;                                                              \
      a0 = __builtin_amdgcn_mfma_f32_16x16x32_f16(afA0[0], bf0, fzero, 0, 0, 0); \
      a0 = __builtin_amdgcn_mfma_f32_16x16x32_f16(afA0[1], bf1, a0, 0, 0, 0);    \
      a1 = __builtin_amdgcn_mfma_f32_16x16x32_f16(afA1[0], bf0, fzero, 0, 0, 0); \
      a1 = __builtin_amdgcn_mfma_f32_16x16x32_f16(afA1[1], bf1, a1, 0, 0, 0);    \
      a1 = __builtin_amdgcn_mfma_f32_16x16x32_f16(afA1[2], bf2, a1, 0, 0, 0);    \
      a1 = __builtin_amdgcn_mfma_f32_16x16x32_f16(afA1[3], bf3, a1, 0, 0, 0);    \
      f4 amA;                                                                 \
      _Pragma("unroll")                                                       \
      for (int i = 0; i < 4; i++) amA[i] = dppmerge_(a0[i], a1[i]);           \
      if (hasB) {                                                             \
        f4 b0v, b1v;                                                          \
        b0v = __builtin_amdgcn_mfma_f32_16x16x32_f16(afB0[0], bf0, fzero, 0, 0, 0); \
        b0v = __builtin_amdgcn_mfma_f32_16x16x32_f16(afB0[1], bf1, b0v, 0, 0, 0);   \
        b1v = __builtin_amdgcn_mfma_f32_16x16x32_f16(afB1[0], bf0, fzero, 0, 0, 0); \
        b1v = __builtin_amdgcn_mfma_f32_16x16x32_f16(afB1[1], bf1, b1v, 0, 0, 0);   \
        b1v = __builtin_amdgcn_mfma_f32_16x16x32_f16(afB1[2], bf2, b1v, 0, 0, 0);   \
        b1v = __builtin_amdgcn_mfma_f32_16x16x32_f16(afB1[3], bf3, b1v, 0, 0, 0);   \
        f4 amB;                                                               \
        _Pragma("unroll")                                                     \
        for (int i = 0; i < 4; i++) amB[i] = dppmerge_(b0v[i], b1v[i]);       \
        DOACT(amA, cmA, wApA[1 - (P)], wvalidA, actp)                         \
        DOACT(amB, cmB, wApB[1 - (P)], wvalidB, actp)                         \
      } else {                                                                \
        DOACT(amA, cmA, wApA[1 - (P)], wvalidA, actp)                         \
      }                                                                       \
    }                                                                         \
    if (DOLD) { xhold = xnew; xq += BI; }                                     \
    __syncthreads();                                                          \
  }

    STEP(0, 1, 0, 1, 1)                   // t = 0   (l0 only; store x[1], load x[2])
    STEP(1, 1, 1, 1, 1)                   // t = 1
    #pragma unroll 1
    for (int it = 0; it < 254; ++it) {    // t = 2 .. 509
        STEP(0, 1, 1, 1, 1)
        STEP(1, 1, 1, 1, 1)
    }
    STEP(0, 1, 1, 1, 0)                   // t = 510 (store x[511], no more loads)
    STEP(1, 1, 1, 0, 0)                   // t = 511
    STEP(0, 0, 1, 0, 0)                   // t = 512 (l1 drain: h1[511] -> B1s[1])
#undef STEP
#undef DOACT

    // ---- epilogue: sigmoid(h1[TT-1] . w_out + b_out); h1[511] in B1s[1] ----
    if (tid < BB) {
        float s = b_out[0];
        #pragma unroll
        for (int u = 0; u < HH; u++) {
            s += w_out[u] * (float)B1s[1][(u >> 3) * 128 + tid * 8 + (u & 7)];
        }
        out[b0 + tid] = sigm_(s);
    }
}

extern "C" void kernel_launch(void* const* d_in, const int* in_sizes, int n_in,
                              void* d_out, int out_size, void* d_ws, size_t ws_size,
                              hipStream_t stream) {
    const float* x     = (const float*)d_in[0];
    const float* w_ih0 = (const float*)d_in[1];
    const float* w_hh0 = (const float*)d_in[2];
    const float* b_ih0 = (const float*)d_in[3];
    const float* b_hh0 = (const float*)d_in[4];
    const float* w_ih1 = (const float*)d_in[5];
    const float* w_hh1 = (const float*)d_in[6];
    const float* b_ih1 = (const float*)d_in[7];
    const float* b_hh1 = (const float*)d_in[8];
    const float* w_out = (const float*)d_in[9];
    const float* b_out = (const float*)d_in[10];
    float* out = (float*)d_out;

    dim3 grid(BTOT / BB);   // 256 blocks -> 1 per CU
    dim3 block(512);        // 8 waves: 6x 2-tile + 1x 1-tile(+x) + 1 x-wave
    lstm2_kernel<<<grid, block, 0, stream>>>(x, w_ih0, w_hh0, b_ih0, b_hh0,
                                             w_ih1, w_hh1, b_ih1, b_hh1,
                                             w_out, b_out, out);
}